// Round 2
// 299.291 us; speedup vs baseline: 1.0537x; 1.0537x over previous
//
#include <hip/hip_runtime.h>

// SimpleNet R6b: R5 + (a) pad-row relabeling so the (tile1, reg .w) tanh
// instruction is dead wave-wide (rows 19,23,27,31 = pad -> skip 1/8 of all
// activation instrs), (b) shared-reciprocal tanh/sigmoid: one v_rcp_f32 per
// 3-4 activations (rcp(prod(e_i+1)) + muls) instead of one per value.
// Trans-op count per 32-px iter: 236 -> 134.
// (R6 failed to compile: local `h2` shadowed the h2 vector typedef. Renamed.)
//
//   h = tanh(W_in[25x3] x); 6x: h = tanh(W[25x25] h); out = sigmoid(W_out[3x25] h)
// Layers as D[m][n] = A[m][k]*B[k][n], mfma_f32_16x16x32_f16, 2 M-tiles,
// 2 N-tiles (32 px/wave-iter), K=32.
//
// Relabeling: B element j of lane-group g = physical row mu(8g+j); physical
// rows carry logical channels via ch_map (pads at rows 19,23,27,28,29,30,31;
// the {19,23,27,31} set is exactly the j=7 / d1.w slot for all g -> that
// activation instruction is skipped, slot packed with literal 0; zero weights
// in the consuming A-columns make any finite value safe).
// Weights pre-scaled: hidden/input *2*log2e (tanh = 1-2*rcp(exp2(acc)+1)),
// output *-log2e (sigmoid = rcp(exp2(acc)+1)).

#define HW_PIX (1024 * 1024)
#define NPIX   (4 * HW_PIX)
#define HID    25
#define DEPTH  6

#define TANH_SCALE 2.8853900817779268f    // 2*log2(e)
#define SIG_SCALE  (-1.4426950408889634f) // -log2(e)

typedef __fp16 h8 __attribute__((ext_vector_type(8)));
typedef __fp16 hpk2 __attribute__((ext_vector_type(2)));
typedef float f32x4 __attribute__((ext_vector_type(4)));

// ws layout: [0,768) h8 frags: hidden A[(l*2+t)*64+q]; [768,832) h8: A_out[q];
// then (byte 13312) float Winp[32][3].
#define WS_WINP_BYTE 13312

__device__ __forceinline__ int mu_map(int k) {
    int g = k >> 3, j = k & 7;
    return (j < 4) ? (4 * g + j) : (16 + 4 * g + (j & 3));
}

// physical row -> logical channel; -1 = pad.
// pads at {19,23,27,28,29,30,31}: {19,23,27,31} kills the j=7/d1.w slot.
__device__ __forceinline__ int ch_map(int m) {
    if (m <= 18) return m;
    if (m >= 20 && m <= 22) return m - 1;
    if (m >= 24 && m <= 26) return m - 2;
    return -1;
}

__global__ __launch_bounds__(256) void prep_kernel(
    const float* __restrict__ w_in, const float* __restrict__ ws,
    const float* __restrict__ w_out, __fp16* __restrict__ wsA,
    float* __restrict__ winp)
{
    int tid = threadIdx.x;
    // hidden A-frags: 12 combos (layer l, tile t) x 64 lanes
    for (int u = tid; u < 12 * 64; u += 256) {
        int q = u & 63, combo = u >> 6;
        int l = combo >> 1, t = combo & 1;
        int m = t * 16 + (q & 15);           // physical out row
        int cm = ch_map(m);                  // logical out channel
        for (int j = 0; j < 8; ++j) {
            int k = (q >> 4) * 8 + j;        // physical k column (0..31)
            int cc = ch_map(mu_map(k));      // logical input channel
            float v = (cm >= 0 && cc >= 0) ? ws[(l * HID + cm) * HID + cc] * TANH_SCALE : 0.0f;
            wsA[u * 8 + j] = (__fp16)v;
        }
    }
    // output A-frag (out channels 0..2 live in physical rows 0..2, ch==identity)
    if (tid < 64) {
        int q = tid, m = q & 15;
        for (int j = 0; j < 8; ++j) {
            int k = (q >> 4) * 8 + j;
            int cc = ch_map(mu_map(k));
            float v = (m < 3 && cc >= 0) ? w_out[m * HID + cc] * SIG_SCALE : 0.0f;
            wsA[(12 * 64 + q) * 8 + j] = (__fp16)v;
        }
    }
    // input weights, mu-ordered rows: winp[k][c] = w_in[ch(mu(k))][c] * scale
    if (tid < 32) {
        int k = tid, c = ch_map(mu_map(k));
        for (int ci = 0; ci < 3; ++ci)
            winp[k * 3 + ci] = (c >= 0) ? w_in[c * 3 + ci] * TANH_SCALE : 0.0f;
    }
}

// ---- shared-reciprocal activations. acc pre-scaled: tanh uses 2log2e*z,
// sigmoid uses -log2e*z. One v_rcp per group; products of (e+1) can't
// overflow: hidden |z| <= row-1-norm(W) ~ 6 -> e <= 2^18, prod4 <= 2^72;
// input layer clamps acc <= 30 -> prod4 <= 2^121. ----
__device__ __forceinline__ void tanh4_shared(float a0, float a1, float a2, float a3,
                                             float& o0, float& o1, float& o2, float& o3) {
    float e0 = __builtin_amdgcn_exp2f(a0), e1 = __builtin_amdgcn_exp2f(a1);
    float e2 = __builtin_amdgcn_exp2f(a2), e3 = __builtin_amdgcn_exp2f(a3);
    float t0 = e0 + 1.0f, t1 = e1 + 1.0f, t2 = e2 + 1.0f, t3 = e3 + 1.0f;
    float p01 = t0 * t1, p23 = t2 * t3;
    float rp = __builtin_amdgcn_rcpf(p01 * p23);
    float q01 = rp * p23, q23 = rp * p01;       // 1/(t0 t1), 1/(t2 t3)
    o0 = fmaf(-2.0f, q01 * t1, 1.0f);
    o1 = fmaf(-2.0f, q01 * t0, 1.0f);
    o2 = fmaf(-2.0f, q23 * t3, 1.0f);
    o3 = fmaf(-2.0f, q23 * t2, 1.0f);
}
__device__ __forceinline__ void tanh3_shared(float a0, float a1, float a2,
                                             float& o0, float& o1, float& o2) {
    float e0 = __builtin_amdgcn_exp2f(a0), e1 = __builtin_amdgcn_exp2f(a1);
    float e2 = __builtin_amdgcn_exp2f(a2);
    float t0 = e0 + 1.0f, t1 = e1 + 1.0f, t2 = e2 + 1.0f;
    float p01 = t0 * t1;
    float rp = __builtin_amdgcn_rcpf(p01 * t2);
    float r2  = rp * p01;                        // 1/t2
    float q01 = rp * t2;                         // 1/(t0 t1)
    o0 = fmaf(-2.0f, q01 * t1, 1.0f);
    o1 = fmaf(-2.0f, q01 * t0, 1.0f);
    o2 = fmaf(-2.0f, r2, 1.0f);
}
__device__ __forceinline__ void sig3_shared(float a0, float a1, float a2,
                                            float& o0, float& o1, float& o2) {
    float e0 = __builtin_amdgcn_exp2f(a0), e1 = __builtin_amdgcn_exp2f(a1);
    float e2 = __builtin_amdgcn_exp2f(a2);
    float t0 = e0 + 1.0f, t1 = e1 + 1.0f, t2 = e2 + 1.0f;
    float p01 = t0 * t1;
    float rp = __builtin_amdgcn_rcpf(p01 * t2);
    o2 = rp * p01;
    float q01 = rp * t2;
    o0 = q01 * t1;
    o1 = q01 * t0;
}

__global__ __launch_bounds__(256, 1) void simplenet_kernel(
    const float* __restrict__ x,     // [4,3,1024,1024]
    const h8* __restrict__ wsA,      // packed A fragments
    const float* __restrict__ winp,  // [32][3] mu-ordered, scaled
    float* __restrict__ out)         // [4,3,1024,1024]
{
    const int lane = threadIdx.x & 63;
    const int wgid = blockIdx.x * 4 + (threadIdx.x >> 6);
    const int g = lane >> 4, col = lane & 15;

    // hoist all weight fragments into registers (reused over 16 iterations)
    h8 A[12];
#pragma unroll
    for (int i = 0; i < 12; ++i) A[i] = wsA[i * 64 + lane];
    h8 Aout = wsA[12 * 64 + lane];

    // input-layer rows this lane computes: mu-ordered rows 8g..8g+7, 3 floats each
    float wi[24];
    {
        const f32x4* wp4 = (const f32x4*)(winp + 8 * g * 3);  // 24 floats, 16B-aligned
#pragma unroll
        for (int i = 0; i < 6; ++i) {
            f32x4 v = wp4[i];
            wi[i * 4 + 0] = v.x; wi[i * 4 + 1] = v.y; wi[i * 4 + 2] = v.z; wi[i * 4 + 3] = v.w;
        }
    }

    const int pbase = wgid * 512;           // 512 consecutive pixels per wave
    const int b = pbase >> 20;              // image index (512 | 2^20: no straddle)
    const int hwb = pbase & (HW_PIX - 1);
    const float* xb = x + (size_t)b * 3 * HW_PIX;
    float* ob = out + (size_t)b * 3 * HW_PIX;

    for (int it = 0; it < 16; ++it) {
        const int hw0 = hwb + it * 32;

        // ---- input layer: lane computes B elems j=0..6 (j=7 slot = pad rows) ----
        h8 B[2];
#pragma unroll
        for (int n = 0; n < 2; ++n) {
            const int hw = hw0 + n * 16 + col;
            float x0 = xb[0 * HW_PIX + hw];
            float x1 = xb[1 * HW_PIX + hw];
            float x2 = xb[2 * HW_PIX + hw];
            float acc[7];
#pragma unroll
            for (int j = 0; j < 7; ++j) {
                float a = wi[j * 3 + 0] * x0;
                a = fmaf(wi[j * 3 + 1], x1, a);
                a = fmaf(wi[j * 3 + 2], x2, a);
                acc[j] = fminf(a, 30.0f);   // overflow guard for shared product
            }
            float th0, th1, th2, th3, th4, th5, th6;
            tanh4_shared(acc[0], acc[1], acc[2], acc[3], th0, th1, th2, th3);
            tanh3_shared(acc[4], acc[5], acc[6], th4, th5, th6);
            union { h8 v; hpk2 p[4]; } u;
            u.p[0] = __builtin_amdgcn_cvt_pkrtz(th0, th1);
            u.p[1] = __builtin_amdgcn_cvt_pkrtz(th2, th3);
            u.p[2] = __builtin_amdgcn_cvt_pkrtz(th4, th5);
            u.p[3] = __builtin_amdgcn_cvt_pkrtz(th6, 0.0f);  // pad slot
            B[n] = u.v;
        }

        // ---- 6 hidden layers: 2 M-tiles x 2 N-tiles MFMA, shared-rcp tanh ----
#pragma unroll
        for (int l = 0; l < 6; ++l) {
#pragma unroll
            for (int n = 0; n < 2; ++n) {
                f32x4 zero = {0.0f, 0.0f, 0.0f, 0.0f};
                f32x4 d0 = __builtin_amdgcn_mfma_f32_16x16x32_f16(A[l * 2 + 0], B[n], zero, 0, 0, 0);
                f32x4 d1 = __builtin_amdgcn_mfma_f32_16x16x32_f16(A[l * 2 + 1], B[n], zero, 0, 0, 0);
                // D tile t reg r = phys row (t*16 + 4g + r); next B elem j:
                //   j<4 -> tile0 reg j ; j>=4 -> tile1 reg j-4.
                // d1.w = rows {19,23,27,31} = all-pad -> no tanh, pack 0.
                float y0, y1, y2, y3, y4, y5, y6;
                tanh4_shared(d0.x, d0.y, d0.z, d0.w, y0, y1, y2, y3);
                tanh3_shared(d1.x, d1.y, d1.z, y4, y5, y6);
                union { h8 v; hpk2 p[4]; } u;
                u.p[0] = __builtin_amdgcn_cvt_pkrtz(y0, y1);
                u.p[1] = __builtin_amdgcn_cvt_pkrtz(y2, y3);
                u.p[2] = __builtin_amdgcn_cvt_pkrtz(y4, y5);
                u.p[3] = __builtin_amdgcn_cvt_pkrtz(y6, 0.0f);
                B[n] = u.v;
            }
        }

        // ---- output layer: 3 channels live in rows 0..2 (g==0 lanes) ----
#pragma unroll
        for (int n = 0; n < 2; ++n) {
            f32x4 zero = {0.0f, 0.0f, 0.0f, 0.0f};
            f32x4 d = __builtin_amdgcn_mfma_f32_16x16x32_f16(Aout, B[n], zero, 0, 0, 0);
            if (g == 0) {
                float s0, s1, s2;
                sig3_shared(d.x, d.y, d.z, s0, s1, s2);
                const int hw = hw0 + n * 16 + col;
                ob[0 * HW_PIX + hw] = s0;
                ob[1 * HW_PIX + hw] = s1;
                ob[2 * HW_PIX + hw] = s2;
            }
        }
    }
}

extern "C" void kernel_launch(void* const* d_in, const int* in_sizes, int n_in,
                              void* d_out, int out_size, void* d_ws, size_t ws_size,
                              hipStream_t stream) {
    const float* x     = (const float*)d_in[0];
    const float* w_in  = (const float*)d_in[1];
    const float* ws    = (const float*)d_in[2];
    const float* w_out = (const float*)d_in[3];
    float* out         = (float*)d_out;

    __fp16* wsA = (__fp16*)d_ws;
    float* winp = (float*)((char*)d_ws + WS_WINP_BYTE);

    hipLaunchKernelGGL(prep_kernel, dim3(1), dim3(256), 0, stream,
                       w_in, ws, w_out, wsA, winp);

    // 8192 waves x 16 iters x 32 px = 4Mi pixels, exact
    hipLaunchKernelGGL(simplenet_kernel, dim3(2048), dim3(256), 0, stream,
                       x, (const h8*)d_ws, winp, out);
}

// Round 3
// 272.335 us; speedup vs baseline: 1.1580x; 1.0990x over previous
//
#include <hip/hip_runtime.h>

// SimpleNet R7: R6b + affine-absorption. tanh(z) = 1 - 2*rcp(exp2(acc)+1);
// since every consumer is linear, feed r = rcp(exp2(acc)+1) directly as the
// MFMA B operand and pre-transform weights: A' = -2*W*scale, plus a bias
// column (sum_c W*scale) in physical k-column 7 (mu-row 19 = pad), with the
// B pad slot (j=7) packing constant 1.0. Deletes the fma(-2,*,1) per value
// and the input-layer clamp. Per-iter VALU ~670 -> ~585, trans unchanged.
//
//   h = tanh(W_in[25x3] x); 6x: h = tanh(W[25x25] h); out = sigmoid(W_out[3x25] h)
// Layers as D[m][n] = A[m][k]*B[k][n], mfma_f32_16x16x32_f16, 2 M-tiles,
// 2 N-tiles (32 px/wave-iter), K=32.
//
// Relabeling: B element j of lane-group g = physical row mu(8g+j); physical
// rows carry logical channels via ch_map (pads at rows 19,23,27,28,29,30,31;
// {19,23,27,31} = the j=7 / d1.w slot for all g -> that activation slot is
// the bias-1.0 carrier; A bias lives only in k=7 (mu=19), k=15/23/31 stay 0).
// Scales: hidden/input *2*log2e (r-domain tanh), output *-log2e (sigmoid=r).

#define HW_PIX (1024 * 1024)
#define NPIX   (4 * HW_PIX)
#define HID    25
#define DEPTH  6

#define TANH_SCALE 2.8853900817779268f    // 2*log2(e)
#define SIG_SCALE  (-1.4426950408889634f) // -log2(e)

typedef __fp16 h8 __attribute__((ext_vector_type(8)));
typedef __fp16 hpk2 __attribute__((ext_vector_type(2)));
typedef float f32x4 __attribute__((ext_vector_type(4)));

// ws layout: [0,768) h8 frags: hidden A[(l*2+t)*64+q]; [768,832) h8: A_out[q];
// then (byte 13312) float Winp[32][3].
#define WS_WINP_BYTE 13312

__device__ __forceinline__ int mu_map(int k) {
    int g = k >> 3, j = k & 7;
    return (j < 4) ? (4 * g + j) : (16 + 4 * g + (j & 3));
}

// physical row -> logical channel; -1 = pad.
__device__ __forceinline__ int ch_map(int m) {
    if (m <= 18) return m;
    if (m >= 20 && m <= 22) return m - 1;
    if (m >= 24 && m <= 26) return m - 2;
    return -1;
}

__global__ __launch_bounds__(256) void prep_kernel(
    const float* __restrict__ w_in, const float* __restrict__ ws,
    const float* __restrict__ w_out, __fp16* __restrict__ wsA,
    float* __restrict__ winp)
{
    int tid = threadIdx.x;
    // hidden A-frags: 12 combos (layer l, tile t) x 64 lanes
    // A'[m,c] = -2*scale*W[m,c]; A'[m, k=7] = scale * sum_c W[m,c] (bias)
    for (int u = tid; u < 12 * 64; u += 256) {
        int q = u & 63, combo = u >> 6;
        int l = combo >> 1, t = combo & 1;
        int m = t * 16 + (q & 15);           // physical out row
        int cm = ch_map(m);                  // logical out channel
        for (int j = 0; j < 8; ++j) {
            int k = (q >> 4) * 8 + j;        // physical k column (0..31)
            float v = 0.0f;
            if (cm >= 0) {
                if (k == 7) {                // bias column (mu=19, pad row)
                    float s = 0.0f;
                    for (int c = 0; c < HID; ++c) s += ws[(l * HID + cm) * HID + c];
                    v = s * TANH_SCALE;
                } else {
                    int cc = ch_map(mu_map(k));
                    if (cc >= 0) v = -2.0f * TANH_SCALE * ws[(l * HID + cm) * HID + cc];
                }
            }
            wsA[u * 8 + j] = (__fp16)v;
        }
    }
    // output A-frag (rows 0..2 = out channels), same transform with SIG_SCALE
    if (tid < 64) {
        int q = tid, m = q & 15;
        for (int j = 0; j < 8; ++j) {
            int k = (q >> 4) * 8 + j;
            float v = 0.0f;
            if (m < 3) {
                if (k == 7) {
                    float s = 0.0f;
                    for (int c = 0; c < HID; ++c) s += w_out[m * HID + c];
                    v = s * SIG_SCALE;
                } else {
                    int cc = ch_map(mu_map(k));
                    if (cc >= 0) v = -2.0f * SIG_SCALE * w_out[m * HID + cc];
                }
            }
            wsA[(12 * 64 + q) * 8 + j] = (__fp16)v;
        }
    }
    // input weights, mu-ordered rows: winp[k][c] = w_in[ch(mu(k))][c] * scale
    // (input layer consumes raw x: no affine absorption here)
    if (tid < 32) {
        int k = tid, c = ch_map(mu_map(k));
        for (int ci = 0; ci < 3; ++ci)
            winp[k * 3 + ci] = (c >= 0) ? w_in[c * 3 + ci] * TANH_SCALE : 0.0f;
    }
}

// ---- shared-reciprocal r-groups: r_i = rcp(exp2(a_i)+1). One v_rcp per
// group. Products can't overflow: hidden |a| <= ~12 -> prod4 <= 2^48; input
// |a| <= ~22 on this data -> prod4 <= 2^90. ----
__device__ __forceinline__ void r4_shared(float a0, float a1, float a2, float a3,
                                          float& r0, float& r1, float& r2, float& r3) {
    float e0 = __builtin_amdgcn_exp2f(a0), e1 = __builtin_amdgcn_exp2f(a1);
    float e2 = __builtin_amdgcn_exp2f(a2), e3 = __builtin_amdgcn_exp2f(a3);
    float t0 = e0 + 1.0f, t1 = e1 + 1.0f, t2 = e2 + 1.0f, t3 = e3 + 1.0f;
    float p01 = t0 * t1, p23 = t2 * t3;
    float rp = __builtin_amdgcn_rcpf(p01 * p23);
    float q01 = rp * p23, q23 = rp * p01;       // 1/(t0 t1), 1/(t2 t3)
    r0 = q01 * t1;
    r1 = q01 * t0;
    r2 = q23 * t3;
    r3 = q23 * t2;
}
__device__ __forceinline__ void r3_shared(float a0, float a1, float a2,
                                          float& r0, float& r1, float& r2) {
    float e0 = __builtin_amdgcn_exp2f(a0), e1 = __builtin_amdgcn_exp2f(a1);
    float e2 = __builtin_amdgcn_exp2f(a2);
    float t0 = e0 + 1.0f, t1 = e1 + 1.0f, t2 = e2 + 1.0f;
    float p01 = t0 * t1;
    float rp = __builtin_amdgcn_rcpf(p01 * t2);
    r2 = rp * p01;                               // 1/t2
    float q01 = rp * t2;                         // 1/(t0 t1)
    r0 = q01 * t1;
    r1 = q01 * t0;
}

__global__ __launch_bounds__(256, 1) void simplenet_kernel(
    const float* __restrict__ x,     // [4,3,1024,1024]
    const h8* __restrict__ wsA,      // packed A fragments
    const float* __restrict__ winp,  // [32][3] mu-ordered, scaled
    float* __restrict__ out)         // [4,3,1024,1024]
{
    const int lane = threadIdx.x & 63;
    const int wgid = blockIdx.x * 4 + (threadIdx.x >> 6);
    const int g = lane >> 4, col = lane & 15;

    // hoist all weight fragments into registers (reused over 16 iterations)
    h8 A[12];
#pragma unroll
    for (int i = 0; i < 12; ++i) A[i] = wsA[i * 64 + lane];
    h8 Aout = wsA[12 * 64 + lane];

    // input-layer rows this lane computes: mu-ordered rows 8g..8g+7, 3 floats each
    float wi[24];
    {
        const f32x4* wp4 = (const f32x4*)(winp + 8 * g * 3);  // 24 floats, 16B-aligned
#pragma unroll
        for (int i = 0; i < 6; ++i) {
            f32x4 v = wp4[i];
            wi[i * 4 + 0] = v.x; wi[i * 4 + 1] = v.y; wi[i * 4 + 2] = v.z; wi[i * 4 + 3] = v.w;
        }
    }

    const int pbase = wgid * 512;           // 512 consecutive pixels per wave
    const int b = pbase >> 20;              // image index (512 | 2^20: no straddle)
    const int hwb = pbase & (HW_PIX - 1);
    const float* xb = x + (size_t)b * 3 * HW_PIX;
    float* ob = out + (size_t)b * 3 * HW_PIX;

    for (int it = 0; it < 16; ++it) {
        const int hw0 = hwb + it * 32;

        // ---- input layer: lane computes r for B elems j=0..6; j=7 = 1.0 ----
        h8 B[2];
#pragma unroll
        for (int n = 0; n < 2; ++n) {
            const int hw = hw0 + n * 16 + col;
            float x0 = xb[0 * HW_PIX + hw];
            float x1 = xb[1 * HW_PIX + hw];
            float x2 = xb[2 * HW_PIX + hw];
            float acc[7];
#pragma unroll
            for (int j = 0; j < 7; ++j) {
                float a = wi[j * 3 + 0] * x0;
                a = fmaf(wi[j * 3 + 1], x1, a);
                acc[j] = fmaf(wi[j * 3 + 2], x2, a);
            }
            float r0, r1, r2, r3, r4, r5, r6;
            r4_shared(acc[0], acc[1], acc[2], acc[3], r0, r1, r2, r3);
            r3_shared(acc[4], acc[5], acc[6], r4, r5, r6);
            union { h8 v; hpk2 p[4]; } u;
            u.p[0] = __builtin_amdgcn_cvt_pkrtz(r0, r1);
            u.p[1] = __builtin_amdgcn_cvt_pkrtz(r2, r3);
            u.p[2] = __builtin_amdgcn_cvt_pkrtz(r4, r5);
            u.p[3] = __builtin_amdgcn_cvt_pkrtz(r6, 1.0f);  // bias slot
            B[n] = u.v;
        }

        // ---- 6 hidden layers: 2 M-tiles x 2 N-tiles MFMA, shared-rcp r ----
#pragma unroll
        for (int l = 0; l < 6; ++l) {
#pragma unroll
            for (int n = 0; n < 2; ++n) {
                f32x4 zero = {0.0f, 0.0f, 0.0f, 0.0f};
                f32x4 d0 = __builtin_amdgcn_mfma_f32_16x16x32_f16(A[l * 2 + 0], B[n], zero, 0, 0, 0);
                f32x4 d1 = __builtin_amdgcn_mfma_f32_16x16x32_f16(A[l * 2 + 1], B[n], zero, 0, 0, 0);
                // D tile t reg r = phys row (t*16 + 4g + r); next B elem j:
                //   j<4 -> tile0 reg j ; j>=4 -> tile1 reg j-4.
                // d1.w = rows {19,23,27,31} = pad -> bias slot, pack 1.0.
                float y0, y1, y2, y3, y4, y5, y6;
                r4_shared(d0.x, d0.y, d0.z, d0.w, y0, y1, y2, y3);
                r3_shared(d1.x, d1.y, d1.z, y4, y5, y6);
                union { h8 v; hpk2 p[4]; } u;
                u.p[0] = __builtin_amdgcn_cvt_pkrtz(y0, y1);
                u.p[1] = __builtin_amdgcn_cvt_pkrtz(y2, y3);
                u.p[2] = __builtin_amdgcn_cvt_pkrtz(y4, y5);
                u.p[3] = __builtin_amdgcn_cvt_pkrtz(y6, 1.0f);
                B[n] = u.v;
            }
        }

        // ---- output layer: sigmoid == r; channels in rows 0..2 (g==0) ----
#pragma unroll
        for (int n = 0; n < 2; ++n) {
            f32x4 zero = {0.0f, 0.0f, 0.0f, 0.0f};
            f32x4 d = __builtin_amdgcn_mfma_f32_16x16x32_f16(Aout, B[n], zero, 0, 0, 0);
            if (g == 0) {
                float s0, s1, s2;
                r3_shared(d.x, d.y, d.z, s0, s1, s2);
                const int hw = hw0 + n * 16 + col;
                ob[0 * HW_PIX + hw] = s0;
                ob[1 * HW_PIX + hw] = s1;
                ob[2 * HW_PIX + hw] = s2;
            }
        }
    }
}

extern "C" void kernel_launch(void* const* d_in, const int* in_sizes, int n_in,
                              void* d_out, int out_size, void* d_ws, size_t ws_size,
                              hipStream_t stream) {
    const float* x     = (const float*)d_in[0];
    const float* w_in  = (const float*)d_in[1];
    const float* ws    = (const float*)d_in[2];
    const float* w_out = (const float*)d_in[3];
    float* out         = (float*)d_out;

    __fp16* wsA = (__fp16*)d_ws;
    float* winp = (float*)((char*)d_ws + WS_WINP_BYTE);

    hipLaunchKernelGGL(prep_kernel, dim3(1), dim3(256), 0, stream,
                       w_in, ws, w_out, wsA, winp);

    // 8192 waves x 16 iters x 32 px = 4Mi pixels, exact
    hipLaunchKernelGGL(simplenet_kernel, dim3(2048), dim3(256), 0, stream,
                       x, (const h8*)d_ws, winp, out);
}

// Round 5
// 266.886 us; speedup vs baseline: 1.1817x; 1.0204x over previous
//
#include <hip/hip_runtime.h>

// SimpleNet R8: R7 + direct per-value rcp (revert shared-reciprocal).
// After R7's affine absorption the activation is just r = rcp(exp2(a)+1):
// no per-value tail remains, so sharing one rcp across 3-4 values trades
// 70 rcps/iter (280 cyc) for 222 muls/iter (444 cyc) - a net loss. Direct
// rcp: per 7-group 78 vs 88 issue-cyc and a 3-deep (vs 6-deep) dep chain.
//
//   h = tanh(W_in[25x3] x); 6x: h = tanh(W[25x25] h); out = sigmoid(W_out[3x25] h)
// Layers as D[m][n] = A[m][k]*B[k][n], mfma_f32_16x16x32_f16, 2 M-tiles,
// 2 N-tiles (32 px/wave-iter), K=32. B operand carries r-values;
// A' = -2*scale*W with bias column sum_c(W)*scale at k=7 (mu-row 19 = pad),
// B pad slot (j=7 / d1.w) packs constant 1.0.
//
// Relabeling: B element j of lane-group g = physical row mu(8g+j); physical
// rows carry logical channels via ch_map (pads at rows 19,23,27,28,29,30,31).
// Scales: hidden/input *2*log2e (r-domain tanh), output *-log2e (sigmoid=r).

#define HW_PIX (1024 * 1024)
#define NPIX   (4 * HW_PIX)
#define HID    25
#define DEPTH  6

#define TANH_SCALE 2.8853900817779268f    // 2*log2(e)
#define SIG_SCALE  (-1.4426950408889634f) // -log2(e)

typedef __fp16 h8 __attribute__((ext_vector_type(8)));
typedef __fp16 hpk2 __attribute__((ext_vector_type(2)));
typedef float f32x4 __attribute__((ext_vector_type(4)));

// ws layout: [0,768) h8 frags: hidden A[(l*2+t)*64+q]; [768,832) h8: A_out[q];
// then (byte 13312) float Winp[32][3].
#define WS_WINP_BYTE 13312

__device__ __forceinline__ int mu_map(int k) {
    int g = k >> 3, j = k & 7;
    return (j < 4) ? (4 * g + j) : (16 + 4 * g + (j & 3));
}

// physical row -> logical channel; -1 = pad.
__device__ __forceinline__ int ch_map(int m) {
    if (m <= 18) return m;
    if (m >= 20 && m <= 22) return m - 1;
    if (m >= 24 && m <= 26) return m - 2;
    return -1;
}

__global__ __launch_bounds__(256) void prep_kernel(
    const float* __restrict__ w_in, const float* __restrict__ ws,
    const float* __restrict__ w_out, __fp16* __restrict__ wsA,
    float* __restrict__ winp)
{
    int tid = threadIdx.x;
    // hidden A-frags: 12 combos (layer l, tile t) x 64 lanes
    // A'[m,c] = -2*scale*W[m,c]; A'[m, k=7] = scale * sum_c W[m,c] (bias)
    for (int u = tid; u < 12 * 64; u += 256) {
        int q = u & 63, combo = u >> 6;
        int l = combo >> 1, t = combo & 1;
        int m = t * 16 + (q & 15);           // physical out row
        int cm = ch_map(m);                  // logical out channel
        for (int j = 0; j < 8; ++j) {
            int k = (q >> 4) * 8 + j;        // physical k column (0..31)
            float v = 0.0f;
            if (cm >= 0) {
                if (k == 7) {                // bias column (mu=19, pad row)
                    float s = 0.0f;
                    for (int c = 0; c < HID; ++c) s += ws[(l * HID + cm) * HID + c];
                    v = s * TANH_SCALE;
                } else {
                    int cc = ch_map(mu_map(k));
                    if (cc >= 0) v = -2.0f * TANH_SCALE * ws[(l * HID + cm) * HID + cc];
                }
            }
            wsA[u * 8 + j] = (__fp16)v;
        }
    }
    // output A-frag (rows 0..2 = out channels), same transform with SIG_SCALE
    if (tid < 64) {
        int q = tid, m = q & 15;
        for (int j = 0; j < 8; ++j) {
            int k = (q >> 4) * 8 + j;
            float v = 0.0f;
            if (m < 3) {
                if (k == 7) {
                    float s = 0.0f;
                    for (int c = 0; c < HID; ++c) s += w_out[m * HID + c];
                    v = s * SIG_SCALE;
                } else {
                    int cc = ch_map(mu_map(k));
                    if (cc >= 0) v = -2.0f * SIG_SCALE * w_out[m * HID + cc];
                }
            }
            wsA[(12 * 64 + q) * 8 + j] = (__fp16)v;
        }
    }
    // input weights, mu-ordered rows: winp[k][c] = w_in[ch(mu(k))][c] * scale
    // (input layer consumes raw x: no affine absorption here)
    if (tid < 32) {
        int k = tid, c = ch_map(mu_map(k));
        for (int ci = 0; ci < 3; ++ci)
            winp[k * 3 + ci] = (c >= 0) ? w_in[c * 3 + ci] * TANH_SCALE : 0.0f;
    }
}

// r = rcp(exp2(a)+1): 2 trans + 1 add, 3-deep chain.
__device__ __forceinline__ float ract(float a) {
    return __builtin_amdgcn_rcpf(__builtin_amdgcn_exp2f(a) + 1.0f);
}

__global__ __launch_bounds__(256, 1) void simplenet_kernel(
    const float* __restrict__ x,     // [4,3,1024,1024]
    const h8* __restrict__ wsA,      // packed A fragments
    const float* __restrict__ winp,  // [32][3] mu-ordered, scaled
    float* __restrict__ out)         // [4,3,1024,1024]
{
    const int lane = threadIdx.x & 63;
    const int wgid = blockIdx.x * 4 + (threadIdx.x >> 6);
    const int g = lane >> 4, col = lane & 15;

    // hoist all weight fragments into registers (reused over 16 iterations)
    h8 A[12];
#pragma unroll
    for (int i = 0; i < 12; ++i) A[i] = wsA[i * 64 + lane];
    h8 Aout = wsA[12 * 64 + lane];

    // input-layer rows this lane computes: mu-ordered rows 8g..8g+7, 3 floats each
    float wi[24];
    {
        const f32x4* wp4 = (const f32x4*)(winp + 8 * g * 3);  // 24 floats, 16B-aligned
#pragma unroll
        for (int i = 0; i < 6; ++i) {
            f32x4 v = wp4[i];
            wi[i * 4 + 0] = v.x; wi[i * 4 + 1] = v.y; wi[i * 4 + 2] = v.z; wi[i * 4 + 3] = v.w;
        }
    }

    const int pbase = wgid * 512;           // 512 consecutive pixels per wave
    const int b = pbase >> 20;              // image index (512 | 2^20: no straddle)
    const int hwb = pbase & (HW_PIX - 1);
    const float* xb = x + (size_t)b * 3 * HW_PIX;
    float* ob = out + (size_t)b * 3 * HW_PIX;

    for (int it = 0; it < 16; ++it) {
        const int hw0 = hwb + it * 32;

        // ---- input layer: lane computes r for B elems j=0..6; j=7 = 1.0 ----
        h8 B[2];
#pragma unroll
        for (int n = 0; n < 2; ++n) {
            const int hw = hw0 + n * 16 + col;
            float x0 = xb[0 * HW_PIX + hw];
            float x1 = xb[1 * HW_PIX + hw];
            float x2 = xb[2 * HW_PIX + hw];
            float acc[7];
#pragma unroll
            for (int j = 0; j < 7; ++j) {
                float a = wi[j * 3 + 0] * x0;
                a = fmaf(wi[j * 3 + 1], x1, a);
                acc[j] = fmaf(wi[j * 3 + 2], x2, a);
            }
            union { h8 v; hpk2 p[4]; } u;
            u.p[0] = __builtin_amdgcn_cvt_pkrtz(ract(acc[0]), ract(acc[1]));
            u.p[1] = __builtin_amdgcn_cvt_pkrtz(ract(acc[2]), ract(acc[3]));
            u.p[2] = __builtin_amdgcn_cvt_pkrtz(ract(acc[4]), ract(acc[5]));
            u.p[3] = __builtin_amdgcn_cvt_pkrtz(ract(acc[6]), 1.0f);  // bias slot
            B[n] = u.v;
        }

        // ---- 6 hidden layers: 2 M-tiles x 2 N-tiles MFMA, direct-rcp r ----
#pragma unroll
        for (int l = 0; l < 6; ++l) {
#pragma unroll
            for (int n = 0; n < 2; ++n) {
                f32x4 zero = {0.0f, 0.0f, 0.0f, 0.0f};
                f32x4 d0 = __builtin_amdgcn_mfma_f32_16x16x32_f16(A[l * 2 + 0], B[n], zero, 0, 0, 0);
                f32x4 d1 = __builtin_amdgcn_mfma_f32_16x16x32_f16(A[l * 2 + 1], B[n], zero, 0, 0, 0);
                // D tile t reg r = phys row (t*16 + 4g + r); next B elem j:
                //   j<4 -> tile0 reg j ; j>=4 -> tile1 reg j-4.
                // d1.w = rows {19,23,27,31} = pad -> bias slot, pack 1.0.
                union { h8 v; hpk2 p[4]; } u;
                u.p[0] = __builtin_amdgcn_cvt_pkrtz(ract(d0.x), ract(d0.y));
                u.p[1] = __builtin_amdgcn_cvt_pkrtz(ract(d0.z), ract(d0.w));
                u.p[2] = __builtin_amdgcn_cvt_pkrtz(ract(d1.x), ract(d1.y));
                u.p[3] = __builtin_amdgcn_cvt_pkrtz(ract(d1.z), 1.0f);
                B[n] = u.v;
            }
        }

        // ---- output layer: sigmoid == r; channels in rows 0..2 (g==0) ----
#pragma unroll
        for (int n = 0; n < 2; ++n) {
            f32x4 zero = {0.0f, 0.0f, 0.0f, 0.0f};
            f32x4 d = __builtin_amdgcn_mfma_f32_16x16x32_f16(Aout, B[n], zero, 0, 0, 0);
            if (g == 0) {
                const int hw = hw0 + n * 16 + col;
                ob[0 * HW_PIX + hw] = ract(d.x);
                ob[1 * HW_PIX + hw] = ract(d.y);
                ob[2 * HW_PIX + hw] = ract(d.z);
            }
        }
    }
}

extern "C" void kernel_launch(void* const* d_in, const int* in_sizes, int n_in,
                              void* d_out, int out_size, void* d_ws, size_t ws_size,
                              hipStream_t stream) {
    const float* x     = (const float*)d_in[0];
    const float* w_in  = (const float*)d_in[1];
    const float* ws    = (const float*)d_in[2];
    const float* w_out = (const float*)d_in[3];
    float* out         = (float*)d_out;

    __fp16* wsA = (__fp16*)d_ws;
    float* winp = (float*)((char*)d_ws + WS_WINP_BYTE);

    hipLaunchKernelGGL(prep_kernel, dim3(1), dim3(256), 0, stream,
                       w_in, ws, w_out, wsA, winp);

    // 8192 waves x 16 iters x 32 px = 4Mi pixels, exact
    hipLaunchKernelGGL(simplenet_kernel, dim3(2048), dim3(256), 0, stream,
                       x, (const h8*)d_ws, winp, out);
}